// Round 4
// baseline (380.789 us; speedup 1.0000x reference)
//
#include <hip/hip_runtime.h>

// SudokuLoss v4: dense coalesced staging + wave-compacted sparse compute.
// B=65536, G=9, C=10, mask = (puzzles==0) density ~10%.
// Per block: 8 tiles x 8 puzzles. Per tile:
//   1) stage puzzles(u8)+targets(int4) coalesced -> LDS
//   2) stage logits as float4, GATED per-vector by mask (~34% of lines),
//      lane-consecutive so loads stay coalesced; build per-wave worklist of
//      masked cells via ballot+prefix
//   3) one compacted softmax body pass (~16 active lanes/wave vs 3 dense passes)
//      accumulating row/col/box sums via LDS atomics
//   4) MSE phase over 216 (puzzle,group) pairs, re-zeroing acc for next tile
// All global traffic is dense float4/int4 streams (no strided/scalar gather).

constexpr int kB            = 65536;
constexpr int kPuzzPerTile  = 8;
constexpr int kCellsPerTile = kPuzzPerTile * 81;    // 648
constexpr int kFloatsPerTile= kCellsPerTile * 10;   // 6480
constexpr int kVec4PerTile  = kFloatsPerTile / 4;   // 1620
constexpr int kBlocks       = 1024;
constexpr int kTilesPerBlk  = kB / (kBlocks * kPuzzPerTile);  // 8

__global__ __launch_bounds__(256) void sudoku_main(
    const float* __restrict__ logits,
    const int*   __restrict__ targets,
    const int*   __restrict__ puzzles,
    float*       __restrict__ ws)  // [0,1024): diff2, [1024,2048): ce, [2048,3072): mcnt
{
    __shared__ float         lgs[kFloatsPerTile];          // 25920 B
    __shared__ unsigned char pzs[kCellsPerTile];           //   648 B
    __shared__ int           tgs[kCellsPerTile];           //  2592 B
    __shared__ float         acc[kPuzzPerTile][27][10];    //  8640 B
    __shared__ unsigned short wl[4][164];                  //  1312 B
    __shared__ float         red[4][3];

    const int tid  = threadIdx.x;
    const int wave = tid >> 6;
    const int lane = tid & 63;

    for (int i = tid; i < kPuzzPerTile * 270; i += 256) ((float*)acc)[i] = 0.f;

    float diff2 = 0.f, ce = 0.f, mcnt = 0.f;

    for (int it = 0; it < kTilesPerBlk; ++it) {
        const size_t tile     = (size_t)blockIdx.x * kTilesPerBlk + it;
        const size_t cellBase = tile * kCellsPerTile;

        // ---- stage puzzles (as bytes) + targets, coalesced int4 ----
        if (tid < kCellsPerTile / 4) {   // 162
            const int4 v = ((const int4*)(puzzles + cellBase))[tid];
            unsigned char* p = &pzs[4 * tid];
            p[0] = (unsigned char)v.x; p[1] = (unsigned char)v.y;
            p[2] = (unsigned char)v.z; p[3] = (unsigned char)v.w;
            ((int4*)tgs)[tid] = ((const int4*)(targets + cellBase))[tid];
        }
        __syncthreads();

        // ---- gated logits staging (coalesced float4, ~34% lanes on) ----
        {
            const float4* lg4 = (const float4*)(logits + cellBase * 10);
            #pragma unroll
            for (int k = tid; k < kVec4PerTile; k += 256) {
                const int f0 = 4 * k;
                const int c0 = f0 / 10;
                const int c1 = (f0 + 3) / 10;
                if ((pzs[c0] == 0) || (pzs[c1] == 0))
                    ((float4*)lgs)[k] = lg4[k];
            }
        }

        // ---- per-wave worklist of masked cells (this wave owns 162 cells) ----
        int wcount = 0;
        {
            const int wbase = wave * 162;
            #pragma unroll
            for (int rb = 0; rb < 162; rb += 64) {
                const int ci = rb + lane;
                const bool m = (ci < 162) && (pzs[wbase + ci] == 0);
                const unsigned long long bal = __ballot(m);
                const int pre = __popcll(bal & ((1ULL << lane) - 1ULL));
                if (m) wl[wave][wcount + pre] = (unsigned short)(wbase + ci);
                wcount += (int)__popcll(bal);
            }
        }
        __syncthreads();   // lgs visible to all (wl is same-wave)

        // ---- compacted softmax body: ~wcount (E=16) active lanes, 1 pass ----
        for (int i = lane; i < wcount; i += 64) {
            const int cid = wl[wave][i];
            const float* xp = &lgs[cid * 10];   // 40B-aligned
            float x[10];
            #pragma unroll
            for (int h = 0; h < 5; ++h) {
                const float2 v = *(const float2*)(xp + 2 * h);
                x[2 * h] = v.x; x[2 * h + 1] = v.y;
            }
            float mx = x[0];
            #pragma unroll
            for (int c = 1; c < 10; ++c) mx = fmaxf(mx, x[c]);
            float e[10], S = 0.f;
            #pragma unroll
            for (int c = 0; c < 10; ++c) { e[c] = __expf(x[c] - mx); S += e[c]; }
            const float inv = 1.f / S;
            const float lse = __logf(S);

            const int t = tgs[cid];
            float xt = x[0];
            #pragma unroll
            for (int c = 1; c < 10; ++c) xt = (t == c) ? x[c] : xt;
            ce   += mx + lse - xt;
            mcnt += 1.f;

            const int q    = cid / 81;
            const int cell = cid - q * 81;
            const int r    = cell / 9;
            const int cj   = cell - r * 9;
            const int bx   = (r / 3) * 3 + (cj / 3);
            float* A = &acc[q][0][0];
            float* rowa = A + r * 10;
            float* cola = A + (9 + cj) * 10;
            float* boxa = A + (18 + bx) * 10;
            atomicAdd(&rowa[0], 1.f);
            atomicAdd(&cola[0], 1.f);
            atomicAdd(&boxa[0], 1.f);
            #pragma unroll
            for (int c = 1; c < 10; ++c) {
                const float w = e[c] * inv;
                atomicAdd(&rowa[c], w);
                atomicAdd(&cola[c], w);
                atomicAdd(&boxa[c], w);
            }
        }
        __syncthreads();

        // ---- MSE phase: 216 (puzzle,group) pairs; read then re-zero ----
        if (tid < kPuzzPerTile * 27) {
            const int q = tid / 27;
            const int g = tid - q * 27;
            float* a = &acc[q][g][0];
            const float tg = a[0] * (1.f / 9.f);
            #pragma unroll
            for (int c = 1; c < 10; ++c) { const float d = a[c] - tg; diff2 += d * d; }
            #pragma unroll
            for (int c = 0; c < 10; ++c) a[c] = 0.f;
        }
        __syncthreads();
    }

    // ---- block reduction ----
    #pragma unroll
    for (int off = 32; off > 0; off >>= 1) {
        diff2 += __shfl_down(diff2, off);
        ce    += __shfl_down(ce, off);
        mcnt  += __shfl_down(mcnt, off);
    }
    if (lane == 0) { red[wave][0] = diff2; red[wave][1] = ce; red[wave][2] = mcnt; }
    __syncthreads();
    if (tid == 0) {
        float d = 0.f, c2 = 0.f, m = 0.f;
        #pragma unroll
        for (int wv = 0; wv < 4; ++wv) { d += red[wv][0]; c2 += red[wv][1]; m += red[wv][2]; }
        const int b = blockIdx.x;
        ws[b]                = d;
        ws[kBlocks + b]      = c2;
        ws[2 * kBlocks + b]  = m;
    }
}

__global__ __launch_bounds__(256) void sudoku_final(
    const float* __restrict__ ws, float* __restrict__ out)
{
    __shared__ float red[4][3];
    float s0 = 0.f, s1 = 0.f, s2 = 0.f;
    for (int i = threadIdx.x; i < kBlocks; i += 256) {
        s0 += ws[i];
        s1 += ws[kBlocks + i];
        s2 += ws[2 * kBlocks + i];
    }
    #pragma unroll
    for (int off = 32; off > 0; off >>= 1) {
        s0 += __shfl_down(s0, off);
        s1 += __shfl_down(s1, off);
        s2 += __shfl_down(s2, off);
    }
    const int wave = threadIdx.x >> 6;
    if ((threadIdx.x & 63) == 0) { red[wave][0] = s0; red[wave][1] = s1; red[wave][2] = s2; }
    __syncthreads();
    if (threadIdx.x == 0) {
        float d = 0.f, c2 = 0.f, m = 0.f;
        #pragma unroll
        for (int wv = 0; wv < 4; ++wv) { d += red[wv][0]; c2 += red[wv][1]; m += red[wv][2]; }
        const float ce_loss    = c2 / (m + 1e-8f);
        const float constraint = d / ((float)kB * 9.f * 27.f);
        out[0] = ce_loss + 0.1f * constraint;
        out[1] = ce_loss;
        out[2] = constraint;
    }
}

extern "C" void kernel_launch(void* const* d_in, const int* in_sizes, int n_in,
                              void* d_out, int out_size, void* d_ws, size_t ws_size,
                              hipStream_t stream)
{
    const float* logits  = (const float*)d_in[0];
    const int*   targets = (const int*)d_in[1];
    const int*   puzzles = (const int*)d_in[2];
    float* ws  = (float*)d_ws;
    float* out = (float*)d_out;

    sudoku_main<<<kBlocks, 256, 0, stream>>>(logits, targets, puzzles, ws);
    sudoku_final<<<1, 256, 0, stream>>>(ws, out);
}

// Round 5
// 374.728 us; speedup vs baseline: 1.0162x; 1.0162x over previous
//
#include <hip/hip_runtime.h>

// SudokuLoss v5: barrier-free wave-autonomous streaming.
// B=65536, G=9, C=10. 1024 blocks x 4 waves; each WAVE owns 16 consecutive
// puzzles = 8 stages x 2 puzzles. Per stage:
//   - dense coalesced float4 loads -> registers (prefetched one stage ahead)
//   - registers -> wave-private LDS (ds_write_b128, peak LDS BW)
//   - cell-per-lane softmax from LDS (162 cells / 64 lanes, 3 passes)
//   - row/col/box accumulation: LDS atomics gated by mask (~10% lanes)
//   - per-stage MSE over 54 groups, re-zero acc
// NO __syncthreads in the loop: all LDS is wave-private and DS ops from a
// single wave complete in order (lgkmcnt decrements in order for DS).

constexpr int kB             = 65536;
constexpr int kBlocks        = 1024;
constexpr int kWavesPerBlk   = 4;
constexpr int kWaves         = kBlocks * kWavesPerBlk;   // 4096
constexpr int kStages        = 8;
constexpr int kPuzzPerStage  = 2;
constexpr int kCellsPerStage = kPuzzPerStage * 81;       // 162
constexpr int kVec4PerStage  = kCellsPerStage * 10 / 4;  // 405
constexpr int kAccFloats     = kPuzzPerStage * 27 * 10;  // 540

__global__ __launch_bounds__(256) void sudoku_main(
    const float* __restrict__ logits,
    const int*   __restrict__ targets,
    const int*   __restrict__ puzzles,
    float*       __restrict__ ws)  // [0,4096): diff2, [4096,8192): ce, [8192,12288): mcnt
{
    __shared__ float lgs[kWavesPerBlk][kVec4PerStage * 4];  // 6480 B/wave
    __shared__ float accs[kWavesPerBlk][kAccFloats];        // 2160 B/wave

    const int tid  = threadIdx.x;
    const int wave = tid >> 6;
    const int lane = tid & 63;
    float* Lg = lgs[wave];
    float* Ac = accs[wave];

    // zero wave-private accumulator (in-order DS: visible to stage-0 atomics)
    for (int i = lane; i < kAccFloats; i += 64) Ac[i] = 0.f;

    const int wgid = blockIdx.x * kWavesPerBlk + wave;      // 0..4095
    const size_t puzz0 = (size_t)wgid * (kStages * kPuzzPerStage);
    const float4* lgbase = (const float4*)(logits + puzz0 * 810);
    const int*    pzbase = puzzles + puzz0 * 81;
    const int*    tgbase = targets + puzz0 * 81;

    float4 nxt[7];
    int pzn[3], tgn[3];
    // prologue: stage 0 loads (independent, batched by compiler)
    #pragma unroll
    for (int k = 0; k < 7; ++k) {
        const int v = 64 * k + lane;
        if (v < kVec4PerStage) nxt[k] = lgbase[v];
    }
    #pragma unroll
    for (int k = 0; k < 3; ++k) {
        const int c = 64 * k + lane;
        if (c < kCellsPerStage) { pzn[k] = pzbase[c]; tgn[k] = tgbase[c]; }
    }

    float diff2 = 0.f, ce = 0.f, mcnt = 0.f;

    #pragma unroll 2
    for (int s = 0; s < kStages; ++s) {
        float4 cur[7];
        int pzc[3], tgc[3];
        #pragma unroll
        for (int k = 0; k < 7; ++k) cur[k] = nxt[k];
        #pragma unroll
        for (int k = 0; k < 3; ++k) { pzc[k] = pzn[k]; tgc[k] = tgn[k]; }

        // stage current registers -> wave-private LDS (coalesced b128)
        #pragma unroll
        for (int k = 0; k < 7; ++k) {
            const int v = 64 * k + lane;
            if (v < kVec4PerStage) ((float4*)Lg)[v] = cur[k];
        }

        // prefetch next stage into registers (overlaps with compute below)
        if (s + 1 < kStages) {
            const float4* nb  = lgbase + (size_t)(s + 1) * kVec4PerStage;
            const int*    npz = pzbase + (s + 1) * kCellsPerStage;
            const int*    ntg = tgbase + (s + 1) * kCellsPerStage;
            #pragma unroll
            for (int k = 0; k < 7; ++k) {
                const int v = 64 * k + lane;
                if (v < kVec4PerStage) nxt[k] = nb[v];
            }
            #pragma unroll
            for (int k = 0; k < 3; ++k) {
                const int c = 64 * k + lane;
                if (c < kCellsPerStage) { pzn[k] = npz[c]; tgn[k] = ntg[c]; }
            }
        }

        // compute: 162 cells, cell-per-lane, 3 passes
        #pragma unroll
        for (int k = 0; k < 3; ++k) {
            const int c = 64 * k + lane;
            if (c < kCellsPerStage) {
                const float* xp = Lg + c * 10;
                float x[10];
                #pragma unroll
                for (int h = 0; h < 5; ++h) {
                    const float2 v = *(const float2*)(xp + 2 * h);
                    x[2 * h] = v.x; x[2 * h + 1] = v.y;
                }
                float mx = x[0];
                #pragma unroll
                for (int cc = 1; cc < 10; ++cc) mx = fmaxf(mx, x[cc]);
                float e[10], S = 0.f;
                #pragma unroll
                for (int cc = 0; cc < 10; ++cc) { e[cc] = __expf(x[cc] - mx); S += e[cc]; }
                const float inv = 1.f / S;
                const float lse = __logf(S);

                const int pz = pzc[k];
                const int t  = tgc[k];
                float xt = x[0];
                #pragma unroll
                for (int cc = 1; cc < 10; ++cc) xt = (t == cc) ? x[cc] : xt;
                const float maskf = (pz == 0) ? 1.f : 0.f;
                ce   += maskf * (mx + lse - xt);
                mcnt += maskf;

                if (pz == 0) {   // ~10% lanes -> cheap gated LDS atomics
                    const int q   = c / 81;
                    const int c81 = c - 81 * q;
                    const int r   = c81 / 9;
                    const int cj  = c81 - 9 * r;
                    const int bx  = (r / 3) * 3 + (cj / 3);
                    float* A    = Ac + q * 270;
                    float* rowa = A + r * 10;
                    float* cola = A + (9 + cj) * 10;
                    float* boxa = A + (18 + bx) * 10;
                    atomicAdd(&rowa[0], 1.f);
                    atomicAdd(&cola[0], 1.f);
                    atomicAdd(&boxa[0], 1.f);
                    #pragma unroll
                    for (int cc = 1; cc < 10; ++cc) {
                        const float w = e[cc] * inv;
                        atomicAdd(&rowa[cc], w);
                        atomicAdd(&cola[cc], w);
                        atomicAdd(&boxa[cc], w);
                    }
                }
            }
        }

        // MSE over 54 (puzzle,group) pairs; read then re-zero (in-order DS)
        if (lane < kPuzzPerStage * 27) {
            float* a = Ac + lane * 10;
            const float tg9 = a[0] * (1.f / 9.f);
            #pragma unroll
            for (int cc = 1; cc < 10; ++cc) { const float d = a[cc] - tg9; diff2 += d * d; }
            #pragma unroll
            for (int cc = 0; cc < 10; ++cc) a[cc] = 0.f;
        }
    }

    // wave reduction, one global write per wave (no cross-wave LDS, no barrier)
    #pragma unroll
    for (int off = 32; off > 0; off >>= 1) {
        diff2 += __shfl_down(diff2, off);
        ce    += __shfl_down(ce, off);
        mcnt  += __shfl_down(mcnt, off);
    }
    if (lane == 0) {
        ws[wgid]              = diff2;
        ws[kWaves + wgid]     = ce;
        ws[2 * kWaves + wgid] = mcnt;
    }
}

__global__ __launch_bounds__(256) void sudoku_final(
    const float* __restrict__ ws, float* __restrict__ out)
{
    __shared__ float red[4][3];
    float s0 = 0.f, s1 = 0.f, s2 = 0.f;
    for (int i = threadIdx.x; i < kWaves; i += 256) {
        s0 += ws[i];
        s1 += ws[kWaves + i];
        s2 += ws[2 * kWaves + i];
    }
    #pragma unroll
    for (int off = 32; off > 0; off >>= 1) {
        s0 += __shfl_down(s0, off);
        s1 += __shfl_down(s1, off);
        s2 += __shfl_down(s2, off);
    }
    const int wave = threadIdx.x >> 6;
    if ((threadIdx.x & 63) == 0) { red[wave][0] = s0; red[wave][1] = s1; red[wave][2] = s2; }
    __syncthreads();
    if (threadIdx.x == 0) {
        float d = 0.f, c2 = 0.f, m = 0.f;
        #pragma unroll
        for (int wv = 0; wv < 4; ++wv) { d += red[wv][0]; c2 += red[wv][1]; m += red[wv][2]; }
        const float ce_loss    = c2 / (m + 1e-8f);
        const float constraint = d / ((float)kB * 9.f * 27.f);
        out[0] = ce_loss + 0.1f * constraint;
        out[1] = ce_loss;
        out[2] = constraint;
    }
}

extern "C" void kernel_launch(void* const* d_in, const int* in_sizes, int n_in,
                              void* d_out, int out_size, void* d_ws, size_t ws_size,
                              hipStream_t stream)
{
    const float* logits  = (const float*)d_in[0];
    const int*   targets = (const int*)d_in[1];
    const int*   puzzles = (const int*)d_in[2];
    float* ws  = (float*)d_ws;
    float* out = (float*)d_out;

    sudoku_main<<<kBlocks, 256, 0, stream>>>(logits, targets, puzzles, ws);
    sudoku_final<<<1, 256, 0, stream>>>(ws, out);
}

// Round 6
// 366.950 us; speedup vs baseline: 1.0377x; 1.0212x over previous
//
#include <hip/hip_runtime.h>

// SudokuLoss v6: barrier-free wave-autonomous streaming, NO cross-stage
// register prefetch (v5's cur[]/nxt[] float4 arrays spilled to scratch:
// WRITE_SIZE=196MB, VGPR=52 -> compiler spilled; this version keeps all
// temporaries intra-stage and caps occupancy via __launch_bounds__(256,4)
// so the allocator has a 128-VGPR budget and never spills).
// 1024 blocks x 4 waves; each WAVE owns 16 puzzles = 8 stages x 2 puzzles.
// Per stage: dense coalesced float4 -> short-lived regs -> wave-private LDS,
// cell-per-lane softmax, mask-gated LDS atomics, per-stage MSE. No
// __syncthreads in the loop (wave-private LDS, DS ops in-order per wave).

constexpr int kB             = 65536;
constexpr int kBlocks        = 1024;
constexpr int kWavesPerBlk   = 4;
constexpr int kWaves         = kBlocks * kWavesPerBlk;   // 4096
constexpr int kStages        = 8;
constexpr int kPuzzPerStage  = 2;
constexpr int kCellsPerStage = kPuzzPerStage * 81;       // 162
constexpr int kVec4PerStage  = kCellsPerStage * 10 / 4;  // 405
constexpr int kAccFloats     = kPuzzPerStage * 27 * 10;  // 540

__global__ __launch_bounds__(256, 4) void sudoku_main(
    const float* __restrict__ logits,
    const int*   __restrict__ targets,
    const int*   __restrict__ puzzles,
    float*       __restrict__ ws)  // [0,4096): diff2, [4096,8192): ce, [8192,12288): mcnt
{
    __shared__ float lgs[kWavesPerBlk][kVec4PerStage * 4];  // 6480 B/wave
    __shared__ float accs[kWavesPerBlk][kAccFloats];        // 2160 B/wave

    const int tid  = threadIdx.x;
    const int wave = tid >> 6;
    const int lane = tid & 63;
    float* Lg = lgs[wave];
    float* Ac = accs[wave];

    for (int i = lane; i < kAccFloats; i += 64) Ac[i] = 0.f;

    const int wgid = blockIdx.x * kWavesPerBlk + wave;      // 0..4095
    const size_t puzz0 = (size_t)wgid * (kStages * kPuzzPerStage);
    const float4* lgbase = (const float4*)(logits + puzz0 * 810);
    const int*    pzbase = puzzles + puzz0 * 81;
    const int*    tgbase = targets + puzz0 * 81;

    float diff2 = 0.f, ce = 0.f, mcnt = 0.f;

    for (int s = 0; s < kStages; ++s) {
        const float4* lg4 = lgbase + (size_t)s * kVec4PerStage;
        const int*    pzs = pzbase + s * kCellsPerStage;
        const int*    tgs = tgbase + s * kCellsPerStage;

        // ---- dense coalesced loads (short-lived regs), then -> LDS ----
        float4 tmp[7];
        int pzc[3], tgc[3];
        #pragma unroll
        for (int k = 0; k < 7; ++k) {
            const int v = 64 * k + lane;
            if (v < kVec4PerStage) tmp[k] = lg4[v];
        }
        #pragma unroll
        for (int k = 0; k < 3; ++k) {
            const int c = 64 * k + lane;
            if (c < kCellsPerStage) { pzc[k] = pzs[c]; tgc[k] = tgs[c]; }
        }
        #pragma unroll
        for (int k = 0; k < 7; ++k) {
            const int v = 64 * k + lane;
            if (v < kVec4PerStage) ((float4*)Lg)[v] = tmp[k];
        }

        // ---- compute: 162 cells, cell-per-lane, 3 passes ----
        #pragma unroll
        for (int k = 0; k < 3; ++k) {
            const int c = 64 * k + lane;
            if (c < kCellsPerStage) {
                const float* xp = Lg + c * 10;
                float x[10];
                #pragma unroll
                for (int h = 0; h < 5; ++h) {
                    const float2 v = *(const float2*)(xp + 2 * h);
                    x[2 * h] = v.x; x[2 * h + 1] = v.y;
                }
                float mx = x[0];
                #pragma unroll
                for (int cc = 1; cc < 10; ++cc) mx = fmaxf(mx, x[cc]);
                float e[10], S = 0.f;
                #pragma unroll
                for (int cc = 0; cc < 10; ++cc) { e[cc] = __expf(x[cc] - mx); S += e[cc]; }
                const float inv = 1.f / S;
                const float lse = __logf(S);

                const int pz = pzc[k];
                const int t  = tgc[k];
                float xt = x[0];
                #pragma unroll
                for (int cc = 1; cc < 10; ++cc) xt = (t == cc) ? x[cc] : xt;
                const float maskf = (pz == 0) ? 1.f : 0.f;
                ce   += maskf * (mx + lse - xt);
                mcnt += maskf;

                if (pz == 0) {   // ~10% lanes -> cheap gated LDS atomics
                    const int q   = c / 81;
                    const int c81 = c - 81 * q;
                    const int r   = c81 / 9;
                    const int cj  = c81 - 9 * r;
                    const int bx  = (r / 3) * 3 + (cj / 3);
                    float* A    = Ac + q * 270;
                    float* rowa = A + r * 10;
                    float* cola = A + (9 + cj) * 10;
                    float* boxa = A + (18 + bx) * 10;
                    atomicAdd(&rowa[0], 1.f);
                    atomicAdd(&cola[0], 1.f);
                    atomicAdd(&boxa[0], 1.f);
                    #pragma unroll
                    for (int cc = 1; cc < 10; ++cc) {
                        const float w = e[cc] * inv;
                        atomicAdd(&rowa[cc], w);
                        atomicAdd(&cola[cc], w);
                        atomicAdd(&boxa[cc], w);
                    }
                }
            }
        }

        // ---- MSE over 54 (puzzle,group) pairs; read then re-zero ----
        if (lane < kPuzzPerStage * 27) {
            float* a = Ac + lane * 10;
            const float tg9 = a[0] * (1.f / 9.f);
            #pragma unroll
            for (int cc = 1; cc < 10; ++cc) { const float d = a[cc] - tg9; diff2 += d * d; }
            #pragma unroll
            for (int cc = 0; cc < 10; ++cc) a[cc] = 0.f;
        }
    }

    // wave reduction, one global write per wave (no cross-wave LDS, no barrier)
    #pragma unroll
    for (int off = 32; off > 0; off >>= 1) {
        diff2 += __shfl_down(diff2, off);
        ce    += __shfl_down(ce, off);
        mcnt  += __shfl_down(mcnt, off);
    }
    if (lane == 0) {
        ws[wgid]              = diff2;
        ws[kWaves + wgid]     = ce;
        ws[2 * kWaves + wgid] = mcnt;
    }
}

__global__ __launch_bounds__(256) void sudoku_final(
    const float* __restrict__ ws, float* __restrict__ out)
{
    __shared__ float red[4][3];
    float s0 = 0.f, s1 = 0.f, s2 = 0.f;
    for (int i = threadIdx.x; i < kWaves; i += 256) {
        s0 += ws[i];
        s1 += ws[kWaves + i];
        s2 += ws[2 * kWaves + i];
    }
    #pragma unroll
    for (int off = 32; off > 0; off >>= 1) {
        s0 += __shfl_down(s0, off);
        s1 += __shfl_down(s1, off);
        s2 += __shfl_down(s2, off);
    }
    const int wave = threadIdx.x >> 6;
    if ((threadIdx.x & 63) == 0) { red[wave][0] = s0; red[wave][1] = s1; red[wave][2] = s2; }
    __syncthreads();
    if (threadIdx.x == 0) {
        float d = 0.f, c2 = 0.f, m = 0.f;
        #pragma unroll
        for (int wv = 0; wv < 4; ++wv) { d += red[wv][0]; c2 += red[wv][1]; m += red[wv][2]; }
        const float ce_loss    = c2 / (m + 1e-8f);
        const float constraint = d / ((float)kB * 9.f * 27.f);
        out[0] = ce_loss + 0.1f * constraint;
        out[1] = ce_loss;
        out[2] = constraint;
    }
}

extern "C" void kernel_launch(void* const* d_in, const int* in_sizes, int n_in,
                              void* d_out, int out_size, void* d_ws, size_t ws_size,
                              hipStream_t stream)
{
    const float* logits  = (const float*)d_in[0];
    const int*   targets = (const int*)d_in[1];
    const int*   puzzles = (const int*)d_in[2];
    float* ws  = (float*)d_ws;
    float* out = (float*)d_out;

    sudoku_main<<<kBlocks, 256, 0, stream>>>(logits, targets, puzzles, ws);
    sudoku_final<<<1, 256, 0, stream>>>(ws, out);
}